// Round 5
// baseline (744.864 us; speedup 1.0000x reference)
//
#include <hip/hip_runtime.h>
#include <hip/hip_bf16.h>
#include <math.h>

// ---------------- problem constants (fixed by reference module) -------------
#define NB      2
#define LQ      12240
#define LEN_IN  12240
#define CMODEL  256
#define KDIM    256
#define MHEADS  8
#define NLEV    4
#define NPTS    4
#define DHEAD   32
#define MROWS   (NB * LQ)   // 24480
#define NFUSE   384         // offsets(256) | logits(128)

typedef __attribute__((ext_vector_type(8))) short  bf16x8;
typedef __attribute__((ext_vector_type(4))) float  f32x4;

__device__ __constant__ int c_H[4]  = {96, 48, 24, 12};
__device__ __constant__ int c_W[4]  = {96, 48, 24, 12};
__device__ __constant__ int c_ST[4] = {0, 9216, 11520, 12096};

// ---------- transpose + f32->bf16: W [K][N] f32  ->  Wt [N][K] bf16 ---------
__global__ __launch_bounds__(256)
void transpose_bf16(const float* __restrict__ W, __hip_bfloat16* __restrict__ Wt,
                    int K, int N)
{
    __shared__ float t[32][33];
    const int n0 = blockIdx.x * 32, k0 = blockIdx.y * 32;
    const int c = threadIdx.x & 31, r0 = threadIdx.x >> 5;
#pragma unroll
    for (int i = 0; i < 4; ++i) {
        int r = r0 + i * 8;
        t[r][c] = W[(long)(k0 + r) * N + n0 + c];
    }
    __syncthreads();
#pragma unroll
    for (int i = 0; i < 4; ++i) {
        int r = r0 + i * 8;
        Wt[(long)(n0 + r) * K + k0 + c] = __float2bfloat16(t[c][r]);
    }
}

// ---------- concat biases: bcat = [bo(256) | ba(128)] -----------------------
__global__ __launch_bounds__(256)
void concat_bias(const float* __restrict__ bo, const float* __restrict__ ba,
                 float* __restrict__ bcat)
{
    int i = blockIdx.x * 256 + threadIdx.x;
    if (i < 256) bcat[i] = bo[i];
    else if (i < NFUSE) bcat[i] = ba[i - 256];
}

// ---------- bf16 MFMA GEMM: C[M][N] = A[M][256]_f32 * Bt[N][256]_bf16 + bias
__global__ __launch_bounds__(256)
void mfma_gemm(const float* __restrict__ A,
               const __hip_bfloat16* __restrict__ Bt,
               const float* __restrict__ bias,
               float* __restrict__ C,
               int M, int N)
{
    constexpr int BK   = 64;
    constexpr int LDSP = BK + 8;
    __shared__ __hip_bfloat16 As[128][LDSP];
    __shared__ __hip_bfloat16 Bs[128][LDSP];

    const int tid  = threadIdx.x;
    const int lane = tid & 63;
    const int wave = tid >> 6;
    const int wm   = wave >> 1, wn = wave & 1;
    const int bm   = blockIdx.y * 128;
    const int bn   = blockIdx.x * 128;

    f32x4 acc[4][4];
#pragma unroll
    for (int i = 0; i < 4; ++i)
#pragma unroll
        for (int j = 0; j < 4; ++j) acc[i][j] = (f32x4)0.f;

    const int srowA = tid >> 4;
    const int scolA = (tid & 15) * 4;
    const int srowB = tid >> 3;
    const int scolB = (tid & 7) * 8;

    for (int k0 = 0; k0 < KDIM; k0 += BK) {
#pragma unroll
        for (int i = 0; i < 8; ++i) {
            int row  = srowA + i * 16;
            int grow = bm + row; if (grow > M - 1) grow = M - 1;
            float4 v = *(const float4*)&A[(long)grow * KDIM + k0 + scolA];
            ushort4 h;
            __hip_bfloat16 hx = __float2bfloat16(v.x);
            __hip_bfloat16 hy = __float2bfloat16(v.y);
            __hip_bfloat16 hz = __float2bfloat16(v.z);
            __hip_bfloat16 hw = __float2bfloat16(v.w);
            h.x = *(unsigned short*)&hx; h.y = *(unsigned short*)&hy;
            h.z = *(unsigned short*)&hz; h.w = *(unsigned short*)&hw;
            *(ushort4*)&As[row][scolA] = h;
        }
#pragma unroll
        for (int i = 0; i < 4; ++i) {
            int row = srowB + i * 32;
            bf16x8 v = *(const bf16x8*)&Bt[(long)(bn + row) * KDIM + k0 + scolB];
            *(bf16x8*)&Bs[row][scolB] = v;
        }
        __syncthreads();

#pragma unroll
        for (int kc = 0; kc < BK; kc += 32) {
            const int krd = kc + ((lane >> 4) << 3);
            bf16x8 a[4], b[4];
#pragma unroll
            for (int mi = 0; mi < 4; ++mi)
                a[mi] = *(const bf16x8*)&As[wm * 64 + mi * 16 + (lane & 15)][krd];
#pragma unroll
            for (int nj = 0; nj < 4; ++nj)
                b[nj] = *(const bf16x8*)&Bs[wn * 64 + nj * 16 + (lane & 15)][krd];
#pragma unroll
            for (int mi = 0; mi < 4; ++mi)
#pragma unroll
                for (int nj = 0; nj < 4; ++nj)
                    acc[mi][nj] = __builtin_amdgcn_mfma_f32_16x16x32_bf16(
                        a[mi], b[nj], acc[mi][nj], 0, 0, 0);
        }
        __syncthreads();
    }

    const int colb = lane & 15;
    const int rowb = (lane >> 4) * 4;
#pragma unroll
    for (int mi = 0; mi < 4; ++mi) {
#pragma unroll
        for (int r = 0; r < 4; ++r) {
            int grow = bm + wm * 64 + mi * 16 + rowb + r;
            if (grow >= M) continue;
#pragma unroll
            for (int nj = 0; nj < 4; ++nj) {
                int gcol = bn + wn * 64 + nj * 16 + colb;
                C[(long)grow * N + gcol] = acc[mi][nj][r] + bias[gcol];
            }
        }
    }
}

// ---------------- sampling core (shared body) -------------------------------
// fused row layout: [offsets(m,L,P,2) 256 | logits(m,16) 128], stride 384
template<bool UNROLL_LVL>
__device__ __forceinline__ void sample_body(
    const float* __restrict__ value, const float* __restrict__ fused,
    const float* __restrict__ refpts, float* __restrict__ msda, long item)
{
    const int  g  = threadIdx.x & 7;
    const int  m  = (int)(item & (MHEADS - 1));
    const long nq = item >> 3;
    const int  n  = (int)(nq / LQ);

    const float* frow = fused + nq * NFUSE;
    const float* lg   = frow + 256 + m * 16;
    float l[16];
    float mx = -1e30f;
#pragma unroll
    for (int j4 = 0; j4 < 4; ++j4) {
        float4 v = *(const float4*)&lg[j4 * 4];
        l[j4*4+0] = v.x; l[j4*4+1] = v.y; l[j4*4+2] = v.z; l[j4*4+3] = v.w;
    }
#pragma unroll
    for (int j = 0; j < 16; ++j) mx = fmaxf(mx, l[j]);
    float s = 0.f;
#pragma unroll
    for (int j = 0; j < 16; ++j) { l[j] = __expf(l[j] - mx); s += l[j]; }
    const float inv = 1.f / s;

    const float* off = frow + m * 32;
    const float* rp  = refpts + nq * (NLEV * 2);
    const float* vb  = value + (long)n * LEN_IN * CMODEL + m * DHEAD + g * 4;

    f32x4 acc = (f32x4)0.f;
#pragma unroll (UNROLL_LVL ? 4 : 1)
    for (int lvl = 0; lvl < NLEV; ++lvl) {
        const int H = c_H[lvl], W = c_W[lvl], st = c_ST[lvl];
        const float2 r2 = *(const float2*)&rp[lvl * 2];
        const float rxW = r2.x * (float)W;
        const float ryH = r2.y * (float)H;
        const float* base = vb + (long)st * CMODEL;
#pragma unroll
        for (int p = 0; p < NPTS; ++p) {
            const int j = lvl * NPTS + p;
            const float w_attn = l[j] * inv;
            const float2 o2 = *(const float2*)&off[j * 2];
            const float x = rxW + o2.x - 0.5f;
            const float y = ryH + o2.y - 0.5f;
            const float x0f = floorf(x), y0f = floorf(y);
            const int   x0 = (int)x0f,  y0 = (int)y0f;
            const float wx1 = x - x0f, wx0 = 1.f - wx1;
            const float wy1 = y - y0f, wy0 = 1.f - wy1;

            const bool xv0 = (x0 >= 0) & (x0 < W);
            const bool xv1 = (x0 + 1 >= 0) & (x0 + 1 < W);
            const bool yv0 = (y0 >= 0) & (y0 < H);
            const bool yv1 = (y0 + 1 >= 0) & (y0 + 1 < H);
            const int xc0 = min(max(x0, 0), W - 1);
            const int xc1 = min(max(x0 + 1, 0), W - 1);
            const int yc0 = min(max(y0, 0), H - 1);
            const int yc1 = min(max(y0 + 1, 0), H - 1);

            f32x4 v00 = (f32x4)0.f, v01 = (f32x4)0.f;
            f32x4 v10 = (f32x4)0.f, v11 = (f32x4)0.f;
            if (yv0) {
                const float* rowp = base + (long)yc0 * W * CMODEL;
                if (xv0) v00 = *(const f32x4*)&rowp[(long)xc0 * CMODEL];
                if (xv1) v01 = *(const f32x4*)&rowp[(long)xc1 * CMODEL];
            }
            if (yv1) {
                const float* rowp = base + (long)yc1 * W * CMODEL;
                if (xv0) v10 = *(const f32x4*)&rowp[(long)xc0 * CMODEL];
                if (xv1) v11 = *(const f32x4*)&rowp[(long)xc1 * CMODEL];
            }
            acc += w_attn * (wy0 * (wx0 * v00 + wx1 * v01) +
                             wy1 * (wx0 * v10 + wx1 * v11));
        }
    }
    *(f32x4*)&msda[nq * CMODEL + m * DHEAD + g * 4] = acc;
}

// Variant A: full unroll, VGPR capped at 128 (4 waves/SIMD)
__global__ __launch_bounds__(256, 4)
void msda_sampleA(const float* __restrict__ value, const float* __restrict__ fused,
                  const float* __restrict__ refpts, float* __restrict__ msda,
                  long itemBase)
{
    const long item = itemBase + (long)blockIdx.x * 32 + (threadIdx.x >> 3);
    sample_body<true>(value, fused, refpts, msda, item);
}

// Variant B: level loop rolled, VGPR capped at ~85 (6 waves/SIMD)
__global__ __launch_bounds__(256, 6)
void msda_sampleB(const float* __restrict__ value, const float* __restrict__ fused,
                  const float* __restrict__ refpts, float* __restrict__ msda,
                  long itemBase)
{
    const long item = itemBase + (long)blockIdx.x * 32 + (threadIdx.x >> 3);
    sample_body<false>(value, fused, refpts, msda, item);
}

// ---------------------------------------------------------------------------
extern "C" void kernel_launch(void* const* d_in, const int* in_sizes, int n_in,
                              void* d_out, int out_size, void* d_ws, size_t ws_size,
                              hipStream_t stream)
{
    const float* query = (const float*)d_in[0];
    const float* refp  = (const float*)d_in[1];
    const float* inpf  = (const float*)d_in[2];
    const float* Wv    = (const float*)d_in[5];
    const float* bv    = (const float*)d_in[6];
    const float* Wo    = (const float*)d_in[7];
    const float* bo    = (const float*)d_in[8];
    const float* Wa    = (const float*)d_in[9];
    const float* ba    = (const float*)d_in[10];
    const float* Wout  = (const float*)d_in[11];
    const float* bout  = (const float*)d_in[12];
    float* out = (float*)d_out;

    // ws layout (floats): value | fused | msda | bf16 weights | bcat
    float* ws    = (float*)d_ws;
    float* value = ws;                                 // 24480*256
    float* fused = value + (long)MROWS * CMODEL;       // 24480*384
    float* msda  = fused + (long)MROWS * NFUSE;        // 24480*256
    __hip_bfloat16* Wtv  = (__hip_bfloat16*)(msda + (long)MROWS * CMODEL);
    __hip_bfloat16* Wtc  = Wtv + 256 * 256;            // [Wo|Wa]^T: 384x256
    __hip_bfloat16* Wtt  = Wtc + NFUSE * 256;          // Wout^T
    float* bcat = (float*)(Wtt + 256 * 256);           // 384

    const dim3 blk(256);

    // 0) weight prep
    transpose_bf16<<<dim3(8, 8), blk, 0, stream>>>(Wv,   Wtv, 256, 256);
    transpose_bf16<<<dim3(8, 8), blk, 0, stream>>>(Wo,   Wtc, 256, 256);
    transpose_bf16<<<dim3(4, 8), blk, 0, stream>>>(Wa,   Wtc + 256 * 256, 256, 128);
    transpose_bf16<<<dim3(8, 8), blk, 0, stream>>>(Wout, Wtt, 256, 256);
    concat_bias<<<dim3(2), blk, 0, stream>>>(bo, ba, bcat);

    const int gy = (MROWS + 127) / 128;  // 192

    // 1) value = input_flatten @ Wv + bv
    mfma_gemm<<<dim3(2, gy), blk, 0, stream>>>(inpf, Wtv, bv, value, MROWS, 256);
    // 2) fused = query @ [Wo|Wa] + [bo|ba]
    mfma_gemm<<<dim3(3, gy), blk, 0, stream>>>(query, Wtc, bcat, fused, MROWS, NFUSE);
    // 3) sampling — A/B split across the item range
    {
        const long items = (long)NB * LQ * MHEADS;     // 195840
        const long half  = items / 2;                  // 97920 (3060 blocks)
        msda_sampleA<<<dim3((int)(half / 32)), blk, 0, stream>>>(
            value, fused, refp, msda, 0L);
        msda_sampleB<<<dim3((int)((items - half) / 32)), blk, 0, stream>>>(
            value, fused, refp, msda, half);
    }
    // 4) out = msda @ Wout + bout
    mfma_gemm<<<dim3(2, gy), blk, 0, stream>>>(msda, Wtt, bout, out, MROWS, 256);
}

// Round 6
// 332.641 us; speedup vs baseline: 2.2392x; 2.2392x over previous
//
#include <hip/hip_runtime.h>
#include <hip/hip_bf16.h>
#include <math.h>

// ---------------- problem constants (fixed by reference module) -------------
#define NB      2
#define LQ      12240
#define LEN_IN  12240
#define CMODEL  256
#define KDIM    256
#define MHEADS  8
#define NLEV    4
#define NPTS    4
#define DHEAD   32
#define MROWS   (NB * LQ)   // 24480
#define NFUSE   384         // offsets(256) | logits(128)

typedef __attribute__((ext_vector_type(8))) short  bf16x8;
typedef __attribute__((ext_vector_type(4))) float  f32x4;

__device__ __constant__ int c_H[4]  = {96, 48, 24, 12};
__device__ __constant__ int c_W[4]  = {96, 48, 24, 12};
__device__ __constant__ int c_ST[4] = {0, 9216, 11520, 12096};

// ---------- transpose + f32->bf16: W [K][N] f32  ->  Wt [N][K] bf16 ---------
__global__ __launch_bounds__(256)
void transpose_bf16(const float* __restrict__ W, __hip_bfloat16* __restrict__ Wt,
                    int K, int N)
{
    __shared__ float t[32][33];
    const int n0 = blockIdx.x * 32, k0 = blockIdx.y * 32;
    const int c = threadIdx.x & 31, r0 = threadIdx.x >> 5;
#pragma unroll
    for (int i = 0; i < 4; ++i) {
        int r = r0 + i * 8;
        t[r][c] = W[(long)(k0 + r) * N + n0 + c];
    }
    __syncthreads();
#pragma unroll
    for (int i = 0; i < 4; ++i) {
        int r = r0 + i * 8;
        Wt[(long)(n0 + r) * K + k0 + c] = __float2bfloat16(t[c][r]);
    }
}

// ---------- concat biases: bcat = [bo(256) | ba(128)] -----------------------
__global__ __launch_bounds__(256)
void concat_bias(const float* __restrict__ bo, const float* __restrict__ ba,
                 float* __restrict__ bcat)
{
    int i = blockIdx.x * 256 + threadIdx.x;
    if (i < 256) bcat[i] = bo[i];
    else if (i < NFUSE) bcat[i] = ba[i - 256];
}

// ---------- bf16 MFMA GEMM: C[M][N] = A[M][256]_f32 * Bt[N][256]_bf16 + bias
__global__ __launch_bounds__(256)
void mfma_gemm(const float* __restrict__ A,
               const __hip_bfloat16* __restrict__ Bt,
               const float* __restrict__ bias,
               float* __restrict__ C,
               int M, int N)
{
    constexpr int BK   = 64;
    constexpr int LDSP = BK + 8;
    __shared__ __hip_bfloat16 As[128][LDSP];
    __shared__ __hip_bfloat16 Bs[128][LDSP];

    const int tid  = threadIdx.x;
    const int lane = tid & 63;
    const int wave = tid >> 6;
    const int wm   = wave >> 1, wn = wave & 1;
    const int bm   = blockIdx.y * 128;
    const int bn   = blockIdx.x * 128;

    f32x4 acc[4][4];
#pragma unroll
    for (int i = 0; i < 4; ++i)
#pragma unroll
        for (int j = 0; j < 4; ++j) acc[i][j] = (f32x4)0.f;

    const int srowA = tid >> 4;
    const int scolA = (tid & 15) * 4;
    const int srowB = tid >> 3;
    const int scolB = (tid & 7) * 8;

    for (int k0 = 0; k0 < KDIM; k0 += BK) {
#pragma unroll
        for (int i = 0; i < 8; ++i) {
            int row  = srowA + i * 16;
            int grow = bm + row; if (grow > M - 1) grow = M - 1;
            float4 v = *(const float4*)&A[(long)grow * KDIM + k0 + scolA];
            ushort4 h;
            __hip_bfloat16 hx = __float2bfloat16(v.x);
            __hip_bfloat16 hy = __float2bfloat16(v.y);
            __hip_bfloat16 hz = __float2bfloat16(v.z);
            __hip_bfloat16 hw = __float2bfloat16(v.w);
            h.x = *(unsigned short*)&hx; h.y = *(unsigned short*)&hy;
            h.z = *(unsigned short*)&hz; h.w = *(unsigned short*)&hw;
            *(ushort4*)&As[row][scolA] = h;
        }
#pragma unroll
        for (int i = 0; i < 4; ++i) {
            int row = srowB + i * 32;
            bf16x8 v = *(const bf16x8*)&Bt[(long)(bn + row) * KDIM + k0 + scolB];
            *(bf16x8*)&Bs[row][scolB] = v;
        }
        __syncthreads();

#pragma unroll
        for (int kc = 0; kc < BK; kc += 32) {
            const int krd = kc + ((lane >> 4) << 3);
            bf16x8 a[4], b[4];
#pragma unroll
            for (int mi = 0; mi < 4; ++mi)
                a[mi] = *(const bf16x8*)&As[wm * 64 + mi * 16 + (lane & 15)][krd];
#pragma unroll
            for (int nj = 0; nj < 4; ++nj)
                b[nj] = *(const bf16x8*)&Bs[wn * 64 + nj * 16 + (lane & 15)][krd];
#pragma unroll
            for (int mi = 0; mi < 4; ++mi)
#pragma unroll
                for (int nj = 0; nj < 4; ++nj)
                    acc[mi][nj] = __builtin_amdgcn_mfma_f32_16x16x32_bf16(
                        a[mi], b[nj], acc[mi][nj], 0, 0, 0);
        }
        __syncthreads();
    }

    const int colb = lane & 15;
    const int rowb = (lane >> 4) * 4;
#pragma unroll
    for (int mi = 0; mi < 4; ++mi) {
#pragma unroll
        for (int r = 0; r < 4; ++r) {
            int grow = bm + wm * 64 + mi * 16 + rowb + r;
            if (grow >= M) continue;
#pragma unroll
            for (int nj = 0; nj < 4; ++nj) {
                int gcol = bn + wn * 64 + nj * 16 + colb;
                C[(long)grow * N + gcol] = acc[mi][nj][r] + bias[gcol];
            }
        }
    }
}

// ---------------- sampler variant A: round-4 body, natural VGPR -------------
// fused row layout: [offsets(m,L,P,2) 256 | logits(m,16) 128], stride 384
__global__ __launch_bounds__(256)
void msda_sampleA(const float* __restrict__ value, const float* __restrict__ fused,
                  const float* __restrict__ refpts, float* __restrict__ msda,
                  long itemBase)
{
    const int  g    = threadIdx.x & 7;
    const long item = itemBase + (long)blockIdx.x * 32 + (threadIdx.x >> 3);
    const int  m    = (int)(item & (MHEADS - 1));
    const long nq   = item >> 3;
    const int  n    = (int)(nq / LQ);

    const float* frow = fused + nq * NFUSE;
    const float* lg   = frow + 256 + m * 16;
    float l[16];
    float mx = -1e30f;
#pragma unroll
    for (int j4 = 0; j4 < 4; ++j4) {
        float4 v = *(const float4*)&lg[j4 * 4];
        l[j4*4+0] = v.x; l[j4*4+1] = v.y; l[j4*4+2] = v.z; l[j4*4+3] = v.w;
    }
#pragma unroll
    for (int j = 0; j < 16; ++j) mx = fmaxf(mx, l[j]);
    float s = 0.f;
#pragma unroll
    for (int j = 0; j < 16; ++j) { l[j] = __expf(l[j] - mx); s += l[j]; }
    const float inv = 1.f / s;

    const float* off = frow + m * 32;
    const float* rp  = refpts + nq * (NLEV * 2);
    const float* vb  = value + (long)n * LEN_IN * CMODEL + m * DHEAD + g * 4;

    f32x4 acc = (f32x4)0.f;
#pragma unroll
    for (int lvl = 0; lvl < NLEV; ++lvl) {
        const int H = c_H[lvl], W = c_W[lvl], st = c_ST[lvl];
        const float2 r2 = *(const float2*)&rp[lvl * 2];
        const float rxW = r2.x * (float)W;
        const float ryH = r2.y * (float)H;
        const float* base = vb + (long)st * CMODEL;
#pragma unroll
        for (int p = 0; p < NPTS; ++p) {
            const int j = lvl * NPTS + p;
            const float w_attn = l[j] * inv;
            const float2 o2 = *(const float2*)&off[j * 2];
            const float x = rxW + o2.x - 0.5f;
            const float y = ryH + o2.y - 0.5f;
            const float x0f = floorf(x), y0f = floorf(y);
            const int   x0 = (int)x0f,  y0 = (int)y0f;
            const float wx1 = x - x0f, wx0 = 1.f - wx1;
            const float wy1 = y - y0f, wy0 = 1.f - wy1;

            const bool xv0 = (x0 >= 0) & (x0 < W);
            const bool xv1 = (x0 + 1 >= 0) & (x0 + 1 < W);
            const bool yv0 = (y0 >= 0) & (y0 < H);
            const bool yv1 = (y0 + 1 >= 0) & (y0 + 1 < H);
            const int xc0 = min(max(x0, 0), W - 1);
            const int xc1 = min(max(x0 + 1, 0), W - 1);
            const int yc0 = min(max(y0, 0), H - 1);
            const int yc1 = min(max(y0 + 1, 0), H - 1);

            f32x4 v00 = (f32x4)0.f, v01 = (f32x4)0.f;
            f32x4 v10 = (f32x4)0.f, v11 = (f32x4)0.f;
            if (yv0) {
                const float* rowp = base + (long)yc0 * W * CMODEL;
                if (xv0) v00 = *(const f32x4*)&rowp[(long)xc0 * CMODEL];
                if (xv1) v01 = *(const f32x4*)&rowp[(long)xc1 * CMODEL];
            }
            if (yv1) {
                const float* rowp = base + (long)yc1 * W * CMODEL;
                if (xv0) v10 = *(const f32x4*)&rowp[(long)xc0 * CMODEL];
                if (xv1) v11 = *(const f32x4*)&rowp[(long)xc1 * CMODEL];
            }
            acc += w_attn * (wy0 * (wx0 * v00 + wx1 * v01) +
                             wy1 * (wx0 * v10 + wx1 * v11));
        }
    }
    *(f32x4*)&msda[nq * CMODEL + m * DHEAD + g * 4] = acc;
}

// ---------------- sampler variant B: rolled 16-point loop, low VGPR ---------
// No register array indexed at runtime: softmax pass produces scalars (mx, inv);
// the rolled loop re-loads the logit from global (L1-hit) per point.
__global__ __launch_bounds__(256)
void msda_sampleB(const float* __restrict__ value, const float* __restrict__ fused,
                  const float* __restrict__ refpts, float* __restrict__ msda,
                  long itemBase)
{
    const int  g    = threadIdx.x & 7;
    const long item = itemBase + (long)blockIdx.x * 32 + (threadIdx.x >> 3);
    const int  m    = (int)(item & (MHEADS - 1));
    const long nq   = item >> 3;
    const int  n    = (int)(nq / LQ);

    const float* frow = fused + nq * NFUSE;
    const float* lg   = frow + 256 + m * 16;

    // pass 1: max + sum (vectorized, compile-time indices, no live array after)
    float mx = -1e30f;
    {
        float t[16];
#pragma unroll
        for (int j4 = 0; j4 < 4; ++j4) {
            float4 v = *(const float4*)&lg[j4 * 4];
            t[j4*4+0] = v.x; t[j4*4+1] = v.y; t[j4*4+2] = v.z; t[j4*4+3] = v.w;
        }
#pragma unroll
        for (int j = 0; j < 16; ++j) mx = fmaxf(mx, t[j]);
        float s = 0.f;
#pragma unroll
        for (int j = 0; j < 16; ++j) s += __expf(t[j] - mx);
        mx += __logf(s);   // now exp(lg - mx) is already normalized
    }

    const float* off = frow + m * 32;
    const float* rp  = refpts + nq * (NLEV * 2);
    const float* vb  = value + (long)n * LEN_IN * CMODEL + m * DHEAD + g * 4;

    f32x4 acc = (f32x4)0.f;
#pragma unroll 1
    for (int j = 0; j < 16; ++j) {
        const int lvl = j >> 2;
        const int H = c_H[lvl], W = c_W[lvl], st = c_ST[lvl];
        const float2 r2 = *(const float2*)&rp[lvl * 2];
        const float2 o2 = *(const float2*)&off[j * 2];
        const float w_attn = __expf(lg[j] - mx);   // normalized weight
        const float x = r2.x * (float)W + o2.x - 0.5f;
        const float y = r2.y * (float)H + o2.y - 0.5f;
        const float x0f = floorf(x), y0f = floorf(y);
        const int   x0 = (int)x0f,  y0 = (int)y0f;
        const float wx1 = x - x0f, wx0 = 1.f - wx1;
        const float wy1 = y - y0f, wy0 = 1.f - wy1;

        const bool xv0 = (x0 >= 0) & (x0 < W);
        const bool xv1 = (x0 + 1 >= 0) & (x0 + 1 < W);
        const bool yv0 = (y0 >= 0) & (y0 < H);
        const bool yv1 = (y0 + 1 >= 0) & (y0 + 1 < H);
        const int xc0 = min(max(x0, 0), W - 1);
        const int xc1 = min(max(x0 + 1, 0), W - 1);
        const int yc0 = min(max(y0, 0), H - 1);
        const int yc1 = min(max(y0 + 1, 0), H - 1);

        const float* base = vb + (long)st * CMODEL;
        f32x4 v00 = (f32x4)0.f, v01 = (f32x4)0.f;
        f32x4 v10 = (f32x4)0.f, v11 = (f32x4)0.f;
        if (yv0) {
            const float* rowp = base + (long)yc0 * W * CMODEL;
            if (xv0) v00 = *(const f32x4*)&rowp[(long)xc0 * CMODEL];
            if (xv1) v01 = *(const f32x4*)&rowp[(long)xc1 * CMODEL];
        }
        if (yv1) {
            const float* rowp = base + (long)yc1 * W * CMODEL;
            if (xv0) v10 = *(const f32x4*)&rowp[(long)xc0 * CMODEL];
            if (xv1) v11 = *(const f32x4*)&rowp[(long)xc1 * CMODEL];
        }
        acc += w_attn * (wy0 * (wx0 * v00 + wx1 * v01) +
                         wy1 * (wx0 * v10 + wx1 * v11));
    }
    *(f32x4*)&msda[nq * CMODEL + m * DHEAD + g * 4] = acc;
}

// ---------------------------------------------------------------------------
extern "C" void kernel_launch(void* const* d_in, const int* in_sizes, int n_in,
                              void* d_out, int out_size, void* d_ws, size_t ws_size,
                              hipStream_t stream)
{
    const float* query = (const float*)d_in[0];
    const float* refp  = (const float*)d_in[1];
    const float* inpf  = (const float*)d_in[2];
    const float* Wv    = (const float*)d_in[5];
    const float* bv    = (const float*)d_in[6];
    const float* Wo    = (const float*)d_in[7];
    const float* bo    = (const float*)d_in[8];
    const float* Wa    = (const float*)d_in[9];
    const float* ba    = (const float*)d_in[10];
    const float* Wout  = (const float*)d_in[11];
    const float* bout  = (const float*)d_in[12];
    float* out = (float*)d_out;

    // ws layout (floats): value | fused | msda | bf16 weights | bcat
    float* ws    = (float*)d_ws;
    float* value = ws;                                 // 24480*256
    float* fused = value + (long)MROWS * CMODEL;       // 24480*384
    float* msda  = fused + (long)MROWS * NFUSE;        // 24480*256
    __hip_bfloat16* Wtv  = (__hip_bfloat16*)(msda + (long)MROWS * CMODEL);
    __hip_bfloat16* Wtc  = Wtv + 256 * 256;            // [Wo|Wa]^T: 384x256
    __hip_bfloat16* Wtt  = Wtc + NFUSE * 256;          // Wout^T
    float* bcat = (float*)(Wtt + 256 * 256);           // 384

    const dim3 blk(256);

    // 0) weight prep
    transpose_bf16<<<dim3(8, 8), blk, 0, stream>>>(Wv,   Wtv, 256, 256);
    transpose_bf16<<<dim3(8, 8), blk, 0, stream>>>(Wo,   Wtc, 256, 256);
    transpose_bf16<<<dim3(4, 8), blk, 0, stream>>>(Wa,   Wtc + 256 * 256, 256, 128);
    transpose_bf16<<<dim3(8, 8), blk, 0, stream>>>(Wout, Wtt, 256, 256);
    concat_bias<<<dim3(2), blk, 0, stream>>>(bo, ba, bcat);

    const int gy = (MROWS + 127) / 128;  // 192

    // 1) value = input_flatten @ Wv + bv
    mfma_gemm<<<dim3(2, gy), blk, 0, stream>>>(inpf, Wtv, bv, value, MROWS, 256);
    // 2) fused = query @ [Wo|Wa] + [bo|ba]
    mfma_gemm<<<dim3(3, gy), blk, 0, stream>>>(query, Wtc, bcat, fused, MROWS, NFUSE);
    // 3) sampling — A/B split across the item range (within-probe comparison)
    {
        const long items = (long)NB * LQ * MHEADS;     // 195840
        const long half  = items / 2;                  // 97920 (3060 blocks)
        msda_sampleA<<<dim3((int)(half / 32)), blk, 0, stream>>>(
            value, fused, refp, msda, 0L);
        msda_sampleB<<<dim3((int)((items - half) / 32)), blk, 0, stream>>>(
            value, fused, refp, msda, half);
    }
    // 4) out = msda @ Wout + bout
    mfma_gemm<<<dim3(2, gy), blk, 0, stream>>>(msda, Wtt, bout, out, MROWS, 256);
}

// Round 7
// 296.867 us; speedup vs baseline: 2.5091x; 1.1205x over previous
//
#include <hip/hip_runtime.h>
#include <hip/hip_bf16.h>
#include <math.h>

// ---------------- problem constants (fixed by reference module) -------------
#define NB      2
#define LQ      12240
#define LEN_IN  12240
#define CMODEL  256
#define KDIM    256
#define MHEADS  8
#define NLEV    4
#define NPTS    4
#define DHEAD   32
#define MROWS   (NB * LQ)   // 24480
#define NFUSE   384         // offsets(256) | logits(128)

typedef __attribute__((ext_vector_type(8))) short          bf16x8;
typedef __attribute__((ext_vector_type(4))) float          f32x4;
typedef __attribute__((ext_vector_type(4))) unsigned short u16x4;

__device__ __constant__ int c_H[4]  = {96, 48, 24, 12};
__device__ __constant__ int c_W[4]  = {96, 48, 24, 12};
__device__ __constant__ int c_ST[4] = {0, 9216, 11520, 12096};

// ---------- transpose + f32->bf16: W [K][N] f32  ->  Wt [N][K] bf16 ---------
__global__ __launch_bounds__(256)
void transpose_bf16(const float* __restrict__ W, __hip_bfloat16* __restrict__ Wt,
                    int K, int N)
{
    __shared__ float t[32][33];
    const int n0 = blockIdx.x * 32, k0 = blockIdx.y * 32;
    const int c = threadIdx.x & 31, r0 = threadIdx.x >> 5;
#pragma unroll
    for (int i = 0; i < 4; ++i) {
        int r = r0 + i * 8;
        t[r][c] = W[(long)(k0 + r) * N + n0 + c];
    }
    __syncthreads();
#pragma unroll
    for (int i = 0; i < 4; ++i) {
        int r = r0 + i * 8;
        Wt[(long)(n0 + r) * K + k0 + c] = __float2bfloat16(t[c][r]);
    }
}

// ---------- concat biases: bcat = [bo(256) | ba(128)] -----------------------
__global__ __launch_bounds__(256)
void concat_bias(const float* __restrict__ bo, const float* __restrict__ ba,
                 float* __restrict__ bcat)
{
    int i = blockIdx.x * 256 + threadIdx.x;
    if (i < 256) bcat[i] = bo[i];
    else if (i < NFUSE) bcat[i] = ba[i - 256];
}

// ---------- bf16 MFMA GEMM, 64x64 tile, BK=64, 4 waves (2x2 of 32x32) -------
// C = A[M][256]_f32 * Bt[N][256]_bf16 + bias; output f32 or bf16.
template<bool BF16OUT>
__global__ __launch_bounds__(256)
void gemm64(const float* __restrict__ A,
            const __hip_bfloat16* __restrict__ Bt,
            const float* __restrict__ bias,
            void* __restrict__ Cout,
            int M, int N)
{
    constexpr int BK   = 64;
    constexpr int LDSP = BK + 8;   // 144B row stride
    __shared__ __hip_bfloat16 As[64][LDSP];
    __shared__ __hip_bfloat16 Bs[64][LDSP];

    const int tid  = threadIdx.x;
    const int lane = tid & 63;
    const int wave = tid >> 6;
    const int wm   = wave >> 1, wn = wave & 1;
    const int bm   = blockIdx.y * 64;
    const int bn   = blockIdx.x * 64;

    f32x4 acc[2][2];
#pragma unroll
    for (int i = 0; i < 2; ++i)
#pragma unroll
        for (int j = 0; j < 2; ++j) acc[i][j] = (f32x4)0.f;

    const int arow = tid >> 4;            // 0..15 (+16 per pass)
    const int acol = (tid & 15) * 4;      // 0..60
    const int brow = tid >> 3;            // 0..31 (+32 per pass)
    const int bcol = (tid & 7) * 8;       // 0..56

    for (int k0 = 0; k0 < KDIM; k0 += BK) {
#pragma unroll
        for (int p = 0; p < 4; ++p) {
            int row  = arow + p * 16;
            int grow = bm + row; if (grow > M - 1) grow = M - 1;
            float4 v = *(const float4*)&A[(long)grow * KDIM + k0 + acol];
            ushort4 h;
            __hip_bfloat16 hx = __float2bfloat16(v.x);
            __hip_bfloat16 hy = __float2bfloat16(v.y);
            __hip_bfloat16 hz = __float2bfloat16(v.z);
            __hip_bfloat16 hw = __float2bfloat16(v.w);
            h.x = *(unsigned short*)&hx; h.y = *(unsigned short*)&hy;
            h.z = *(unsigned short*)&hz; h.w = *(unsigned short*)&hw;
            *(ushort4*)&As[row][acol] = h;
        }
#pragma unroll
        for (int p = 0; p < 2; ++p) {
            int row = brow + p * 32;
            bf16x8 v = *(const bf16x8*)&Bt[(long)(bn + row) * KDIM + k0 + bcol];
            *(bf16x8*)&Bs[row][bcol] = v;
        }
        __syncthreads();

#pragma unroll
        for (int kc = 0; kc < BK; kc += 32) {
            const int krd = kc + ((lane >> 4) << 3);
            bf16x8 a[2], b[2];
#pragma unroll
            for (int mi = 0; mi < 2; ++mi)
                a[mi] = *(const bf16x8*)&As[wm * 32 + mi * 16 + (lane & 15)][krd];
#pragma unroll
            for (int nj = 0; nj < 2; ++nj)
                b[nj] = *(const bf16x8*)&Bs[wn * 32 + nj * 16 + (lane & 15)][krd];
#pragma unroll
            for (int mi = 0; mi < 2; ++mi)
#pragma unroll
                for (int nj = 0; nj < 2; ++nj)
                    acc[mi][nj] = __builtin_amdgcn_mfma_f32_16x16x32_bf16(
                        a[mi], b[nj], acc[mi][nj], 0, 0, 0);
        }
        __syncthreads();
    }

    // epilogue: C/D layout col=lane&15, row=(lane>>4)*4+reg
    const int colb = lane & 15;
    const int rowb = (lane >> 4) * 4;
#pragma unroll
    for (int mi = 0; mi < 2; ++mi) {
#pragma unroll
        for (int r = 0; r < 4; ++r) {
            int grow = bm + wm * 32 + mi * 16 + rowb + r;
            if (grow >= M) continue;
#pragma unroll
            for (int nj = 0; nj < 2; ++nj) {
                int gcol = bn + wn * 32 + nj * 16 + colb;
                float o = acc[mi][nj][r] + bias[gcol];
                if constexpr (BF16OUT)
                    ((__hip_bfloat16*)Cout)[(long)grow * N + gcol] = __float2bfloat16(o);
                else
                    ((float*)Cout)[(long)grow * N + gcol] = o;
            }
        }
    }
}

// ---------------- sampler: rolled 16-point loop, bf16 value gathers ---------
// fused row layout: [offsets(m,L,P,2) 256 | logits(m,16) 128], stride 384
// UNROLL: 1 or 2 (A/B this round)
template<int UNROLL>
__global__ __launch_bounds__(256)
void msda_sampleB(const __hip_bfloat16* __restrict__ value,
                  const float* __restrict__ fused,
                  const float* __restrict__ refpts, float* __restrict__ msda,
                  long itemBase)
{
    const int  g    = threadIdx.x & 7;
    const long item = itemBase + (long)blockIdx.x * 32 + (threadIdx.x >> 3);
    const int  m    = (int)(item & (MHEADS - 1));
    const long nq   = item >> 3;
    const int  n    = (int)(nq / LQ);

    const float* frow = fused + nq * NFUSE;
    const float* lg   = frow + 256 + m * 16;

    // softmax pass: only scalars survive (mx absorbs log-sum)
    float mx = -1e30f;
    {
        float t[16];
#pragma unroll
        for (int j4 = 0; j4 < 4; ++j4) {
            float4 v = *(const float4*)&lg[j4 * 4];
            t[j4*4+0] = v.x; t[j4*4+1] = v.y; t[j4*4+2] = v.z; t[j4*4+3] = v.w;
        }
#pragma unroll
        for (int j = 0; j < 16; ++j) mx = fmaxf(mx, t[j]);
        float s = 0.f;
#pragma unroll
        for (int j = 0; j < 16; ++j) s += __expf(t[j] - mx);
        mx += __logf(s);   // exp(lg - mx) is now normalized
    }

    const float* off = frow + m * 32;
    const float* rp  = refpts + nq * (NLEV * 2);
    const __hip_bfloat16* vb = value + (long)n * LEN_IN * CMODEL + m * DHEAD + g * 4;

    f32x4 acc = (f32x4)0.f;
#pragma unroll UNROLL
    for (int j = 0; j < 16; ++j) {
        const int lvl = j >> 2;
        const int H = c_H[lvl], W = c_W[lvl], st = c_ST[lvl];
        const float2 r2 = *(const float2*)&rp[lvl * 2];
        const float2 o2 = *(const float2*)&off[j * 2];
        const float w_attn = __expf(lg[j] - mx);
        const float x = r2.x * (float)W + o2.x - 0.5f;
        const float y = r2.y * (float)H + o2.y - 0.5f;
        const float x0f = floorf(x), y0f = floorf(y);
        const int   x0 = (int)x0f,  y0 = (int)y0f;
        const float wx1 = x - x0f, wx0 = 1.f - wx1;
        const float wy1 = y - y0f, wy0 = 1.f - wy1;

        const bool xv0 = (x0 >= 0) & (x0 < W);
        const bool xv1 = (x0 + 1 >= 0) & (x0 + 1 < W);
        const bool yv0 = (y0 >= 0) & (y0 < H);
        const bool yv1 = (y0 + 1 >= 0) & (y0 + 1 < H);
        const int xc0 = min(max(x0, 0), W - 1);
        const int xc1 = min(max(x0 + 1, 0), W - 1);
        const int yc0 = min(max(y0, 0), H - 1);
        const int yc1 = min(max(y0 + 1, 0), H - 1);

        const __hip_bfloat16* base = vb + (long)st * CMODEL;
        f32x4 v00 = (f32x4)0.f, v01 = (f32x4)0.f;
        f32x4 v10 = (f32x4)0.f, v11 = (f32x4)0.f;
        if (yv0) {
            const __hip_bfloat16* rowp = base + (long)yc0 * W * CMODEL;
            if (xv0) {
                u16x4 raw = *(const u16x4*)&rowp[(long)xc0 * CMODEL];
#pragma unroll
                for (int i = 0; i < 4; ++i) v00[i] = __uint_as_float((unsigned)raw[i] << 16);
            }
            if (xv1) {
                u16x4 raw = *(const u16x4*)&rowp[(long)xc1 * CMODEL];
#pragma unroll
                for (int i = 0; i < 4; ++i) v01[i] = __uint_as_float((unsigned)raw[i] << 16);
            }
        }
        if (yv1) {
            const __hip_bfloat16* rowp = base + (long)yc1 * W * CMODEL;
            if (xv0) {
                u16x4 raw = *(const u16x4*)&rowp[(long)xc0 * CMODEL];
#pragma unroll
                for (int i = 0; i < 4; ++i) v10[i] = __uint_as_float((unsigned)raw[i] << 16);
            }
            if (xv1) {
                u16x4 raw = *(const u16x4*)&rowp[(long)xc1 * CMODEL];
#pragma unroll
                for (int i = 0; i < 4; ++i) v11[i] = __uint_as_float((unsigned)raw[i] << 16);
            }
        }
        acc += w_attn * (wy0 * (wx0 * v00 + wx1 * v01) +
                         wy1 * (wx0 * v10 + wx1 * v11));
    }
    *(f32x4*)&msda[nq * CMODEL + m * DHEAD + g * 4] = acc;
}

// ---------------------------------------------------------------------------
extern "C" void kernel_launch(void* const* d_in, const int* in_sizes, int n_in,
                              void* d_out, int out_size, void* d_ws, size_t ws_size,
                              hipStream_t stream)
{
    const float* query = (const float*)d_in[0];
    const float* refp  = (const float*)d_in[1];
    const float* inpf  = (const float*)d_in[2];
    const float* Wv    = (const float*)d_in[5];
    const float* bv    = (const float*)d_in[6];
    const float* Wo    = (const float*)d_in[7];
    const float* bo    = (const float*)d_in[8];
    const float* Wa    = (const float*)d_in[9];
    const float* ba    = (const float*)d_in[10];
    const float* Wout  = (const float*)d_in[11];
    const float* bout  = (const float*)d_in[12];
    float* out = (float*)d_out;

    // ws layout: valueh(bf16) | fused(f32) | msda(f32) | bf16 weights | bcat
    __hip_bfloat16* valueh = (__hip_bfloat16*)d_ws;             // 24480*256 bf16
    float* fused = (float*)(valueh + (long)MROWS * CMODEL);     // 24480*384 f32
    float* msda  = fused + (long)MROWS * NFUSE;                 // 24480*256 f32
    __hip_bfloat16* Wtv = (__hip_bfloat16*)(msda + (long)MROWS * CMODEL);
    __hip_bfloat16* Wtc = Wtv + 256 * 256;                      // [Wo|Wa]^T
    __hip_bfloat16* Wtt = Wtc + NFUSE * 256;                    // Wout^T
    float* bcat = (float*)(Wtt + 256 * 256);                    // 384

    const dim3 blk(256);

    // 0) weight prep
    transpose_bf16<<<dim3(8, 8), blk, 0, stream>>>(Wv,   Wtv, 256, 256);
    transpose_bf16<<<dim3(8, 8), blk, 0, stream>>>(Wo,   Wtc, 256, 256);
    transpose_bf16<<<dim3(4, 8), blk, 0, stream>>>(Wa,   Wtc + 256 * 256, 256, 128);
    transpose_bf16<<<dim3(8, 8), blk, 0, stream>>>(Wout, Wtt, 256, 256);
    concat_bias<<<dim3(2), blk, 0, stream>>>(bo, ba, bcat);

    const int gy = (MROWS + 63) / 64;   // 383

    // 1) value(bf16) = input_flatten @ Wv + bv
    gemm64<true><<<dim3(4, gy), blk, 0, stream>>>(inpf, Wtv, bv, valueh, MROWS, 256);
    // 2) fused = query @ [Wo|Wa] + [bo|ba]
    gemm64<false><<<dim3(6, gy), blk, 0, stream>>>(query, Wtc, bcat, fused, MROWS, NFUSE);
    // 3) sampling — A/B: unroll 1 vs unroll 2 across halves
    {
        const long items = (long)NB * LQ * MHEADS;   // 195840
        const long half  = items / 2;                // 97920 (3060 blocks)
        msda_sampleB<1><<<dim3((int)(half / 32)), blk, 0, stream>>>(
            valueh, fused, refp, msda, 0L);
        msda_sampleB<2><<<dim3((int)((items - half) / 32)), blk, 0, stream>>>(
            valueh, fused, refp, msda, half);
    }
    // 4) out = msda @ Wout + bout
    gemm64<false><<<dim3(4, gy), blk, 0, stream>>>(msda, Wtt, bout, out, MROWS, 256);
}

// Round 8
// 264.836 us; speedup vs baseline: 2.8125x; 1.1209x over previous
//
#include <hip/hip_runtime.h>
#include <hip/hip_bf16.h>
#include <math.h>

// ---------------- problem constants (fixed by reference module) -------------
#define NB      2
#define LQ      12240
#define LEN_IN  12240
#define CMODEL  256
#define KDIM    256
#define MHEADS  8
#define NLEV    4
#define NPTS    4
#define DHEAD   32
#define MROWS   (NB * LQ)   // 24480
#define NFUSE   384         // offsets(256) | logits(128)

typedef __attribute__((ext_vector_type(8))) short          bf16x8;
typedef __attribute__((ext_vector_type(4))) float          f32x4;
typedef __attribute__((ext_vector_type(8))) float          f32x8;
typedef __attribute__((ext_vector_type(4))) unsigned short u16x4;
typedef __attribute__((ext_vector_type(8))) unsigned short u16x8;

__device__ __constant__ int c_H[4]  = {96, 48, 24, 12};
__device__ __constant__ int c_W[4]  = {96, 48, 24, 12};
__device__ __constant__ int c_ST[4] = {0, 9216, 11520, 12096};

__device__ __forceinline__ unsigned short bf16bits(float f) {
    __hip_bfloat16 t = __float2bfloat16(f);
    return *(unsigned short*)&t;
}
__device__ __forceinline__ float bf16val(unsigned short u) {
    return __uint_as_float((unsigned)u << 16);
}

// ---------- f32 -> bf16 bulk convert (8 elems/thread, exact grid) -----------
__global__ __launch_bounds__(256)
void conv_bf16(const float* __restrict__ in, __hip_bfloat16* __restrict__ outh)
{
    const long i = ((long)blockIdx.x * 256 + threadIdx.x) * 8;
    float4 a = *(const float4*)&in[i];
    float4 b = *(const float4*)&in[i + 4];
    u16x8 h;
    h[0]=bf16bits(a.x); h[1]=bf16bits(a.y); h[2]=bf16bits(a.z); h[3]=bf16bits(a.w);
    h[4]=bf16bits(b.x); h[5]=bf16bits(b.y); h[6]=bf16bits(b.z); h[7]=bf16bits(b.w);
    *(u16x8*)&outh[i] = h;
}

// ---------- transpose + f32->bf16: W [K][N] f32 -> Wt [N][K] bf16 -----------
__global__ __launch_bounds__(256)
void transpose_bf16(const float* __restrict__ W, __hip_bfloat16* __restrict__ Wt,
                    int K, int N)
{
    __shared__ float t[32][33];
    const int n0 = blockIdx.x * 32, k0 = blockIdx.y * 32;
    const int c = threadIdx.x & 31, r0 = threadIdx.x >> 5;
#pragma unroll
    for (int i = 0; i < 4; ++i) {
        int r = r0 + i * 8;
        t[r][c] = W[(long)(k0 + r) * N + n0 + c];
    }
    __syncthreads();
#pragma unroll
    for (int i = 0; i < 4; ++i) {
        int r = r0 + i * 8;
        Wt[(long)(n0 + r) * K + k0 + c] = __float2bfloat16(t[c][r]);
    }
}

// ---------- concat biases: bcat = [bo(256) | ba(128)] -----------------------
__global__ __launch_bounds__(256)
void concat_bias(const float* __restrict__ bo, const float* __restrict__ ba,
                 float* __restrict__ bcat)
{
    int i = blockIdx.x * 256 + threadIdx.x;
    if (i < 256) bcat[i] = bo[i];
    else if (i < NFUSE) bcat[i] = ba[i - 256];
}

// ---------- 128x128 bf16 MFMA GEMM core (BK=64, 4 waves 2x2 of 64x64) -------
template<bool BF16OUT>
__device__ __forceinline__ void gemm_core(
    const __hip_bfloat16* __restrict__ A,   // [M][256] bf16
    const __hip_bfloat16* __restrict__ Bt,  // [N][256] bf16
    const float* __restrict__ bias,
    void* __restrict__ Cout, int M, int N, int bm, int bn)
{
    constexpr int LDSP = 72;   // 144B row stride (padded, conflict-light)
    __shared__ __hip_bfloat16 As[128][LDSP];
    __shared__ __hip_bfloat16 Bs[128][LDSP];

    const int tid  = threadIdx.x;
    const int lane = tid & 63;
    const int wave = tid >> 6;
    const int wm   = wave >> 1, wn = wave & 1;

    f32x4 acc[4][4];
#pragma unroll
    for (int i = 0; i < 4; ++i)
#pragma unroll
        for (int j = 0; j < 4; ++j) acc[i][j] = (f32x4)0.f;

    const int srow = tid >> 3;        // 0..31 (+32 per pass)
    const int scol = (tid & 7) * 8;   // 0..56

    for (int k0 = 0; k0 < KDIM; k0 += 64) {
#pragma unroll
        for (int p = 0; p < 4; ++p) {
            int row = srow + p * 32;
            int ga  = bm + row; if (ga > M - 1) ga = M - 1;
            *(bf16x8*)&As[row][scol] =
                *(const bf16x8*)&A[(long)ga * KDIM + k0 + scol];
            *(bf16x8*)&Bs[row][scol] =
                *(const bf16x8*)&Bt[(long)(bn + row) * KDIM + k0 + scol];
        }
        __syncthreads();

#pragma unroll
        for (int kc = 0; kc < 64; kc += 32) {
            const int krd = kc + ((lane >> 4) << 3);
            bf16x8 a[4], b[4];
#pragma unroll
            for (int mi = 0; mi < 4; ++mi)
                a[mi] = *(const bf16x8*)&As[wm * 64 + mi * 16 + (lane & 15)][krd];
#pragma unroll
            for (int nj = 0; nj < 4; ++nj)
                b[nj] = *(const bf16x8*)&Bs[wn * 64 + nj * 16 + (lane & 15)][krd];
#pragma unroll
            for (int mi = 0; mi < 4; ++mi)
#pragma unroll
                for (int nj = 0; nj < 4; ++nj)
                    acc[mi][nj] = __builtin_amdgcn_mfma_f32_16x16x32_bf16(
                        a[mi], b[nj], acc[mi][nj], 0, 0, 0);
        }
        __syncthreads();
    }

    // epilogue: C/D layout col=lane&15, row=(lane>>4)*4+reg
    const int colb = lane & 15;
    const int rowb = (lane >> 4) * 4;
#pragma unroll
    for (int mi = 0; mi < 4; ++mi) {
#pragma unroll
        for (int r = 0; r < 4; ++r) {
            int grow = bm + wm * 64 + mi * 16 + rowb + r;
            if (grow >= M) continue;
#pragma unroll
            for (int nj = 0; nj < 4; ++nj) {
                int gcol = bn + wn * 64 + nj * 16 + colb;
                float o = acc[mi][nj][r] + bias[gcol];
                if constexpr (BF16OUT)
                    ((__hip_bfloat16*)Cout)[(long)grow * N + gcol] = __float2bfloat16(o);
                else
                    ((float*)Cout)[(long)grow * N + gcol] = o;
            }
        }
    }
}

// ---------- stage-1 batched GEMM: value-GEMM (bx<2) + fused-GEMM (bx>=2) ----
__global__ __launch_bounds__(256)
void gemm_stage1(const __hip_bfloat16* __restrict__ i16,
                 const __hip_bfloat16* __restrict__ Wtv,
                 const float* __restrict__ bv,
                 __hip_bfloat16* __restrict__ valueh,
                 const __hip_bfloat16* __restrict__ q16,
                 const __hip_bfloat16* __restrict__ Wtc,
                 const float* __restrict__ bcat,
                 float* __restrict__ fused)
{
    const int bx = blockIdx.x, bm = blockIdx.y * 128;
    if (bx < 2) gemm_core<true >(i16, Wtv, bv,   valueh, MROWS, CMODEL, bm, bx * 128);
    else        gemm_core<false>(q16, Wtc, bcat, fused,  MROWS, NFUSE,  bm, (bx - 2) * 128);
}

// ---------- stage-2 GEMM: out = msda(bf16) @ Wout + bout --------------------
__global__ __launch_bounds__(256)
void gemm_stage2(const __hip_bfloat16* __restrict__ msdah,
                 const __hip_bfloat16* __restrict__ Wtt,
                 const float* __restrict__ bout,
                 float* __restrict__ out)
{
    gemm_core<false>(msdah, Wtt, bout, out, MROWS, CMODEL,
                     blockIdx.y * 128, blockIdx.x * 128);
}

// ---------- sampler variant 8L: 8 lanes/item, u16x4 (8B) taps ---------------
// fused row: [offsets(m,L,P,2) 256 | logits(m,16) 128] f32, stride 384
__global__ __launch_bounds__(256)
void msda_sample8(const __hip_bfloat16* __restrict__ value,
                  const float* __restrict__ fused,
                  const float* __restrict__ refpts,
                  __hip_bfloat16* __restrict__ msdah, long itemBase)
{
    const int  g    = threadIdx.x & 7;
    const long item = itemBase + (long)blockIdx.x * 32 + (threadIdx.x >> 3);
    const int  m    = (int)(item & (MHEADS - 1));
    const long nq   = item >> 3;
    const int  n    = (int)(nq / LQ);

    const float* frow = fused + nq * NFUSE;
    const float* lg   = frow + 256 + m * 16;

    float mx = -1e30f;
    {
        float t[16];
#pragma unroll
        for (int j4 = 0; j4 < 4; ++j4) {
            float4 v = *(const float4*)&lg[j4 * 4];
            t[j4*4+0] = v.x; t[j4*4+1] = v.y; t[j4*4+2] = v.z; t[j4*4+3] = v.w;
        }
#pragma unroll
        for (int j = 0; j < 16; ++j) mx = fmaxf(mx, t[j]);
        float s = 0.f;
#pragma unroll
        for (int j = 0; j < 16; ++j) s += __expf(t[j] - mx);
        mx += __logf(s);   // exp(lg - mx) is normalized
    }

    const float* off = frow + m * 32;
    const float* rp  = refpts + nq * (NLEV * 2);
    const __hip_bfloat16* vb = value + (long)n * LEN_IN * CMODEL + m * DHEAD + g * 4;

    f32x4 acc = (f32x4)0.f;
#pragma unroll 1
    for (int j = 0; j < 16; ++j) {
        const int lvl = j >> 2;
        const int H = c_H[lvl], W = c_W[lvl], st = c_ST[lvl];
        const float2 r2 = *(const float2*)&rp[lvl * 2];
        const float2 o2 = *(const float2*)&off[j * 2];
        const float w_attn = __expf(lg[j] - mx);
        const float x = r2.x * (float)W + o2.x - 0.5f;
        const float y = r2.y * (float)H + o2.y - 0.5f;
        const float x0f = floorf(x), y0f = floorf(y);
        const int   x0 = (int)x0f,  y0 = (int)y0f;
        const float wx1 = x - x0f, wx0 = 1.f - wx1;
        const float wy1 = y - y0f, wy0 = 1.f - wy1;

        const bool xv0 = (x0 >= 0) & (x0 < W);
        const bool xv1 = (x0 + 1 >= 0) & (x0 + 1 < W);
        const bool yv0 = (y0 >= 0) & (y0 < H);
        const bool yv1 = (y0 + 1 >= 0) & (y0 + 1 < H);
        const int xc0 = min(max(x0, 0), W - 1);
        const int xc1 = min(max(x0 + 1, 0), W - 1);
        const int yc0 = min(max(y0, 0), H - 1);
        const int yc1 = min(max(y0 + 1, 0), H - 1);

        const __hip_bfloat16* base = vb + (long)st * CMODEL;
        f32x4 v00 = (f32x4)0.f, v01 = (f32x4)0.f;
        f32x4 v10 = (f32x4)0.f, v11 = (f32x4)0.f;
        if (yv0) {
            const __hip_bfloat16* rowp = base + (long)yc0 * W * CMODEL;
            if (xv0) { u16x4 r = *(const u16x4*)&rowp[(long)xc0 * CMODEL];
#pragma unroll
                for (int i = 0; i < 4; ++i) v00[i] = bf16val(r[i]); }
            if (xv1) { u16x4 r = *(const u16x4*)&rowp[(long)xc1 * CMODEL];
#pragma unroll
                for (int i = 0; i < 4; ++i) v01[i] = bf16val(r[i]); }
        }
        if (yv1) {
            const __hip_bfloat16* rowp = base + (long)yc1 * W * CMODEL;
            if (xv0) { u16x4 r = *(const u16x4*)&rowp[(long)xc0 * CMODEL];
#pragma unroll
                for (int i = 0; i < 4; ++i) v10[i] = bf16val(r[i]); }
            if (xv1) { u16x4 r = *(const u16x4*)&rowp[(long)xc1 * CMODEL];
#pragma unroll
                for (int i = 0; i < 4; ++i) v11[i] = bf16val(r[i]); }
        }
        acc += w_attn * (wy0 * (wx0 * v00 + wx1 * v01) +
                         wy1 * (wx0 * v10 + wx1 * v11));
    }
    u16x4 oh;
#pragma unroll
    for (int i = 0; i < 4; ++i) oh[i] = bf16bits(acc[i]);
    *(u16x4*)&msdah[nq * CMODEL + m * DHEAD + g * 4] = oh;
}

// ---------- sampler variant 4L: 4 lanes/item, bf16x8 (16B) taps -------------
__global__ __launch_bounds__(256)
void msda_sample4L(const __hip_bfloat16* __restrict__ value,
                   const float* __restrict__ fused,
                   const float* __restrict__ refpts,
                   __hip_bfloat16* __restrict__ msdah, long itemBase)
{
    const int  g    = threadIdx.x & 3;
    const long item = itemBase + (long)blockIdx.x * 64 + (threadIdx.x >> 2);
    const int  m    = (int)(item & (MHEADS - 1));
    const long nq   = item >> 3;
    const int  n    = (int)(nq / LQ);

    const float* frow = fused + nq * NFUSE;
    const float* lg   = frow + 256 + m * 16;

    float mx = -1e30f;
    {
        float t[16];
#pragma unroll
        for (int j4 = 0; j4 < 4; ++j4) {
            float4 v = *(const float4*)&lg[j4 * 4];
            t[j4*4+0] = v.x; t[j4*4+1] = v.y; t[j4*4+2] = v.z; t[j4*4+3] = v.w;
        }
#pragma unroll
        for (int j = 0; j < 16; ++j) mx = fmaxf(mx, t[j]);
        float s = 0.f;
#pragma unroll
        for (int j = 0; j < 16; ++j) s += __expf(t[j] - mx);
        mx += __logf(s);
    }

    const float* off = frow + m * 32;
    const float* rp  = refpts + nq * (NLEV * 2);
    const __hip_bfloat16* vb = value + (long)n * LEN_IN * CMODEL + m * DHEAD + g * 8;

    f32x8 acc = (f32x8)0.f;
#pragma unroll 1
    for (int j = 0; j < 16; ++j) {
        const int lvl = j >> 2;
        const int H = c_H[lvl], W = c_W[lvl], st = c_ST[lvl];
        const float2 r2 = *(const float2*)&rp[lvl * 2];
        const float2 o2 = *(const float2*)&off[j * 2];
        const float w_attn = __expf(lg[j] - mx);
        const float x = r2.x * (float)W + o2.x - 0.5f;
        const float y = r2.y * (float)H + o2.y - 0.5f;
        const float x0f = floorf(x), y0f = floorf(y);
        const int   x0 = (int)x0f,  y0 = (int)y0f;
        const float wx1 = x - x0f, wx0 = 1.f - wx1;
        const float wy1 = y - y0f, wy0 = 1.f - wy1;

        const bool xv0 = (x0 >= 0) & (x0 < W);
        const bool xv1 = (x0 + 1 >= 0) & (x0 + 1 < W);
        const bool yv0 = (y0 >= 0) & (y0 < H);
        const bool yv1 = (y0 + 1 >= 0) & (y0 + 1 < H);
        const int xc0 = min(max(x0, 0), W - 1);
        const int xc1 = min(max(x0 + 1, 0), W - 1);
        const int yc0 = min(max(y0, 0), H - 1);
        const int yc1 = min(max(y0 + 1, 0), H - 1);

        const __hip_bfloat16* base = vb + (long)st * CMODEL;
        f32x8 v00 = (f32x8)0.f, v01 = (f32x8)0.f;
        f32x8 v10 = (f32x8)0.f, v11 = (f32x8)0.f;
        if (yv0) {
            const __hip_bfloat16* rowp = base + (long)yc0 * W * CMODEL;
            if (xv0) { u16x8 r = *(const u16x8*)&rowp[(long)xc0 * CMODEL];
#pragma unroll
                for (int i = 0; i < 8; ++i) v00[i] = bf16val(r[i]); }
            if (xv1) { u16x8 r = *(const u16x8*)&rowp[(long)xc1 * CMODEL];
#pragma unroll
                for (int i = 0; i < 8; ++i) v01[i] = bf16val(r[i]); }
        }
        if (yv1) {
            const __hip_bfloat16* rowp = base + (long)yc1 * W * CMODEL;
            if (xv0) { u16x8 r = *(const u16x8*)&rowp[(long)xc0 * CMODEL];
#pragma unroll
                for (int i = 0; i < 8; ++i) v10[i] = bf16val(r[i]); }
            if (xv1) { u16x8 r = *(const u16x8*)&rowp[(long)xc1 * CMODEL];
#pragma unroll
                for (int i = 0; i < 8; ++i) v11[i] = bf16val(r[i]); }
        }
        acc += w_attn * (wy0 * (wx0 * v00 + wx1 * v01) +
                         wy1 * (wx0 * v10 + wx1 * v11));
    }
    u16x8 oh;
#pragma unroll
    for (int i = 0; i < 8; ++i) oh[i] = bf16bits(acc[i]);
    *(u16x8*)&msdah[nq * CMODEL + m * DHEAD + g * 8] = oh;
}

// ---------------------------------------------------------------------------
extern "C" void kernel_launch(void* const* d_in, const int* in_sizes, int n_in,
                              void* d_out, int out_size, void* d_ws, size_t ws_size,
                              hipStream_t stream)
{
    const float* query = (const float*)d_in[0];
    const float* refp  = (const float*)d_in[1];
    const float* inpf  = (const float*)d_in[2];
    const float* Wv    = (const float*)d_in[5];
    const float* bv    = (const float*)d_in[6];
    const float* Wo    = (const float*)d_in[7];
    const float* bo    = (const float*)d_in[8];
    const float* Wa    = (const float*)d_in[9];
    const float* ba    = (const float*)d_in[10];
    const float* Wout  = (const float*)d_in[11];
    const float* bout  = (const float*)d_in[12];
    float* out = (float*)d_out;

    // ws layout: valueh | msdah | q16 | i16 (bf16) | fused (f32) | weights | bcat
    __hip_bfloat16* valueh = (__hip_bfloat16*)d_ws;              // 24480*256
    __hip_bfloat16* msdah  = valueh + (long)MROWS * CMODEL;      // 24480*256
    __hip_bfloat16* q16    = msdah  + (long)MROWS * CMODEL;      // 24480*256
    __hip_bfloat16* i16    = q16    + (long)MROWS * CMODEL;      // 24480*256
    float* fused = (float*)(i16 + (long)MROWS * CMODEL);         // 24480*384 f32
    __hip_bfloat16* Wtv = (__hip_bfloat16*)(fused + (long)MROWS * NFUSE);
    __hip_bfloat16* Wtc = Wtv + 256 * 256;                       // [Wo|Wa]^T
    __hip_bfloat16* Wtt = Wtc + NFUSE * 256;                     // Wout^T
    float* bcat = (float*)(Wtt + 256 * 256);                     // 384

    const dim3 blk(256);
    const int convBlocks = (MROWS * CMODEL) / (256 * 8);         // 3060 exact

    // 0) input converts + weight prep
    conv_bf16<<<dim3(convBlocks), blk, 0, stream>>>(query, q16);
    conv_bf16<<<dim3(convBlocks), blk, 0, stream>>>(inpf,  i16);
    transpose_bf16<<<dim3(8, 8), blk, 0, stream>>>(Wv,   Wtv, 256, 256);
    transpose_bf16<<<dim3(8, 8), blk, 0, stream>>>(Wo,   Wtc, 256, 256);
    transpose_bf16<<<dim3(4, 8), blk, 0, stream>>>(Wa,   Wtc + 256 * 256, 256, 128);
    transpose_bf16<<<dim3(8, 8), blk, 0, stream>>>(Wout, Wtt, 256, 256);
    concat_bias<<<dim3(2), blk, 0, stream>>>(bo, ba, bcat);

    const int gy = (MROWS + 127) / 128;   // 192

    // 1) batched: value(bf16) = i16 @ Wv + bv  |  fused = q16 @ [Wo|Wa] + bcat
    gemm_stage1<<<dim3(5, gy), blk, 0, stream>>>(
        i16, Wtv, bv, valueh, q16, Wtc, bcat, fused);

    // 2) sampling — A/B: 8 lanes/item vs 4 lanes/item across halves
    {
        const long items = (long)NB * LQ * MHEADS;   // 195840
        const long half  = items / 2;                // 97920
        msda_sample8 <<<dim3((int)(half / 32)), blk, 0, stream>>>(
            valueh, fused, refp, msdah, 0L);
        msda_sample4L<<<dim3((int)(half / 64)), blk, 0, stream>>>(
            valueh, fused, refp, msdah, half);
    }

    // 3) out = msdah @ Wout + bout
    gemm_stage2<<<dim3(2, gy), blk, 0, stream>>>(msdah, Wtt, bout, out);
}

// Round 9
// 255.623 us; speedup vs baseline: 2.9139x; 1.0360x over previous
//
#include <hip/hip_runtime.h>
#include <hip/hip_bf16.h>
#include <math.h>

// ---------------- problem constants (fixed by reference module) -------------
#define NB      2
#define LQ      12240
#define LEN_IN  12240
#define CMODEL  256
#define KDIM    256
#define MHEADS  8
#define NLEV    4
#define NPTS    4
#define DHEAD   32
#define MROWS   (NB * LQ)   // 24480
#define NFUSE   384         // offsets(256) | logits(128)

typedef __attribute__((ext_vector_type(8))) short          bf16x8;
typedef __attribute__((ext_vector_type(4))) float          f32x4;
typedef __attribute__((ext_vector_type(8))) float          f32x8;
typedef __attribute__((ext_vector_type(4))) unsigned short u16x4;
typedef __attribute__((ext_vector_type(8))) unsigned short u16x8;

__device__ __constant__ int c_H[4]  = {96, 48, 24, 12};
__device__ __constant__ int c_W[4]  = {96, 48, 24, 12};
__device__ __constant__ int c_ST[4] = {0, 9216, 11520, 12096};

__device__ __forceinline__ unsigned short bf16bits(float f) {
    __hip_bfloat16 t = __float2bfloat16(f);
    return *(unsigned short*)&t;
}
__device__ __forceinline__ float bf16val(unsigned short u) {
    return __uint_as_float((unsigned)u << 16);
}

// ---------- f32 -> bf16 bulk convert (8 elems/thread, exact grid) -----------
__global__ __launch_bounds__(256)
void conv_bf16(const float* __restrict__ in, __hip_bfloat16* __restrict__ outh)
{
    const long i = ((long)blockIdx.x * 256 + threadIdx.x) * 8;
    float4 a = *(const float4*)&in[i];
    float4 b = *(const float4*)&in[i + 4];
    u16x8 h;
    h[0]=bf16bits(a.x); h[1]=bf16bits(a.y); h[2]=bf16bits(a.z); h[3]=bf16bits(a.w);
    h[4]=bf16bits(b.x); h[5]=bf16bits(b.y); h[6]=bf16bits(b.z); h[7]=bf16bits(b.w);
    *(u16x8*)&outh[i] = h;
}

// ---------- transpose + f32->bf16: W [K][N] f32 -> Wt [N][K] bf16 -----------
__global__ __launch_bounds__(256)
void transpose_bf16(const float* __restrict__ W, __hip_bfloat16* __restrict__ Wt,
                    int K, int N)
{
    __shared__ float t[32][33];
    const int n0 = blockIdx.x * 32, k0 = blockIdx.y * 32;
    const int c = threadIdx.x & 31, r0 = threadIdx.x >> 5;
#pragma unroll
    for (int i = 0; i < 4; ++i) {
        int r = r0 + i * 8;
        t[r][c] = W[(long)(k0 + r) * N + n0 + c];
    }
    __syncthreads();
#pragma unroll
    for (int i = 0; i < 4; ++i) {
        int r = r0 + i * 8;
        Wt[(long)(n0 + r) * K + k0 + c] = __float2bfloat16(t[c][r]);
    }
}

// ---------- concat biases: bcat = [bo(256) | ba(128)] -----------------------
__global__ __launch_bounds__(256)
void concat_bias(const float* __restrict__ bo, const float* __restrict__ ba,
                 float* __restrict__ bcat)
{
    int i = blockIdx.x * 256 + threadIdx.x;
    if (i < 256) bcat[i] = bo[i];
    else if (i < NFUSE) bcat[i] = ba[i - 256];
}

// ---------- 128x128 bf16 MFMA GEMM core (BK=64, 4 waves 2x2 of 64x64) -------
template<bool BF16OUT>
__device__ __forceinline__ void gemm_core(
    const __hip_bfloat16* __restrict__ A,   // [M][256] bf16
    const __hip_bfloat16* __restrict__ Bt,  // [N][256] bf16
    const float* __restrict__ bias,
    void* __restrict__ Cout, int M, int N, int bm, int bn)
{
    constexpr int LDSP = 72;   // 144B row stride
    __shared__ __hip_bfloat16 As[128][LDSP];
    __shared__ __hip_bfloat16 Bs[128][LDSP];

    const int tid  = threadIdx.x;
    const int lane = tid & 63;
    const int wave = tid >> 6;
    const int wm   = wave >> 1, wn = wave & 1;

    f32x4 acc[4][4];
#pragma unroll
    for (int i = 0; i < 4; ++i)
#pragma unroll
        for (int j = 0; j < 4; ++j) acc[i][j] = (f32x4)0.f;

    const int srow = tid >> 3;        // 0..31 (+32 per pass)
    const int scol = (tid & 7) * 8;   // 0..56

    for (int k0 = 0; k0 < KDIM; k0 += 64) {
#pragma unroll
        for (int p = 0; p < 4; ++p) {
            int row = srow + p * 32;
            int ga  = bm + row; if (ga > M - 1) ga = M - 1;
            *(bf16x8*)&As[row][scol] =
                *(const bf16x8*)&A[(long)ga * KDIM + k0 + scol];
            *(bf16x8*)&Bs[row][scol] =
                *(const bf16x8*)&Bt[(long)(bn + row) * KDIM + k0 + scol];
        }
        __syncthreads();

#pragma unroll
        for (int kc = 0; kc < 64; kc += 32) {
            const int krd = kc + ((lane >> 4) << 3);
            bf16x8 a[4], b[4];
#pragma unroll
            for (int mi = 0; mi < 4; ++mi)
                a[mi] = *(const bf16x8*)&As[wm * 64 + mi * 16 + (lane & 15)][krd];
#pragma unroll
            for (int nj = 0; nj < 4; ++nj)
                b[nj] = *(const bf16x8*)&Bs[wn * 64 + nj * 16 + (lane & 15)][krd];
#pragma unroll
            for (int mi = 0; mi < 4; ++mi)
#pragma unroll
                for (int nj = 0; nj < 4; ++nj)
                    acc[mi][nj] = __builtin_amdgcn_mfma_f32_16x16x32_bf16(
                        a[mi], b[nj], acc[mi][nj], 0, 0, 0);
        }
        __syncthreads();
    }

    const int colb = lane & 15;
    const int rowb = (lane >> 4) * 4;
#pragma unroll
    for (int mi = 0; mi < 4; ++mi) {
#pragma unroll
        for (int r = 0; r < 4; ++r) {
            int grow = bm + wm * 64 + mi * 16 + rowb + r;
            if (grow >= M) continue;
#pragma unroll
            for (int nj = 0; nj < 4; ++nj) {
                int gcol = bn + wn * 64 + nj * 16 + colb;
                float o = acc[mi][nj][r] + bias[gcol];
                if constexpr (BF16OUT)
                    ((__hip_bfloat16*)Cout)[(long)grow * N + gcol] = __float2bfloat16(o);
                else
                    ((float*)Cout)[(long)grow * N + gcol] = o;
            }
        }
    }
}

// ---------- stage-1 batched GEMM: value-GEMM (bx<2) + fused-GEMM (bx>=2) ----
__global__ __launch_bounds__(256)
void gemm_stage1(const __hip_bfloat16* __restrict__ i16,
                 const __hip_bfloat16* __restrict__ Wtv,
                 const float* __restrict__ bv,
                 __hip_bfloat16* __restrict__ valueh,
                 const __hip_bfloat16* __restrict__ q16,
                 const __hip_bfloat16* __restrict__ Wtc,
                 const float* __restrict__ bcat,
                 float* __restrict__ fused)
{
    const int bx = blockIdx.x, bm = blockIdx.y * 128;
    if (bx < 2) gemm_core<true >(i16, Wtv, bv,   valueh, MROWS, CMODEL, bm, bx * 128);
    else        gemm_core<false>(q16, Wtc, bcat, fused,  MROWS, NFUSE,  bm, (bx - 2) * 128);
}

// ---------- stage-2 GEMM: out = msda(bf16) @ Wout + bout --------------------
__global__ __launch_bounds__(256)
void gemm_stage2(const __hip_bfloat16* __restrict__ msdah,
                 const __hip_bfloat16* __restrict__ Wtt,
                 const float* __restrict__ bout,
                 float* __restrict__ out)
{
    gemm_core<false>(msdah, Wtt, bout, out, MROWS, CMODEL,
                     blockIdx.y * 128, blockIdx.x * 128);
}

// ---------- shared per-point coordinate prep ---------------------------------
struct PointW {
    int   i00, i01, i10, i11;        // pixel indices (clamped), in level frame
    float w00, w01, w10, w11;        // folded weights (0 if invalid)
};
__device__ __forceinline__ PointW point_prep(
    int j, const float* __restrict__ off, const float* __restrict__ rp,
    const float* __restrict__ lg, float mx, int& st)
{
    const int lvl = j >> 2;
    const int H = c_H[lvl], W = c_W[lvl];
    st = c_ST[lvl];
    const float2 r2 = *(const float2*)&rp[lvl * 2];
    const float2 o2 = *(const float2*)&off[j * 2];
    const float w_attn = __expf(lg[j] - mx);
    const float x = r2.x * (float)W + o2.x - 0.5f;
    const float y = r2.y * (float)H + o2.y - 0.5f;
    const float x0f = floorf(x), y0f = floorf(y);
    const int   x0 = (int)x0f,  y0 = (int)y0f;
    const float wx1 = x - x0f, wx0 = 1.f - wx1;
    const float wy1 = y - y0f, wy0 = 1.f - wy1;

    const bool xv0 = (x0 >= 0) & (x0 < W);
    const bool xv1 = (x0 + 1 >= 0) & (x0 + 1 < W);
    const bool yv0 = (y0 >= 0) & (y0 < H);
    const bool yv1 = (y0 + 1 >= 0) & (y0 + 1 < H);
    const int xc0 = min(max(x0, 0), W - 1);
    const int xc1 = min(max(x0 + 1, 0), W - 1);
    const int yc0 = min(max(y0, 0), H - 1);
    const int yc1 = min(max(y0 + 1, 0), H - 1);

    PointW p;
    p.i00 = yc0 * W + xc0;  p.w00 = (xv0 & yv0) ? w_attn * wy0 * wx0 : 0.f;
    p.i01 = yc0 * W + xc1;  p.w01 = (xv1 & yv0) ? w_attn * wy0 * wx1 : 0.f;
    p.i10 = yc1 * W + xc0;  p.w10 = (xv0 & yv1) ? w_attn * wy1 * wx0 : 0.f;
    p.i11 = yc1 * W + xc1;  p.w11 = (xv1 & yv1) ? w_attn * wy1 * wx1 : 0.f;
    return p;
}

__device__ __forceinline__ float item_logsummax(const float* __restrict__ lg)
{
    float t[16];
#pragma unroll
    for (int j4 = 0; j4 < 4; ++j4) {
        float4 v = *(const float4*)&lg[j4 * 4];
        t[j4*4+0] = v.x; t[j4*4+1] = v.y; t[j4*4+2] = v.z; t[j4*4+3] = v.w;
    }
    float mx = -1e30f;
#pragma unroll
    for (int j = 0; j < 16; ++j) mx = fmaxf(mx, t[j]);
    float s = 0.f;
#pragma unroll
    for (int j = 0; j < 16; ++j) s += __expf(t[j] - mx);
    return mx + __logf(s);   // exp(lg - mx') is normalized
}

// ---------- sampler 4L: 4 lanes/item, 8 ch/lane (16B taps) ------------------
__global__ __launch_bounds__(256)
void msda_sample4L(const __hip_bfloat16* __restrict__ value,
                   const float* __restrict__ fused,
                   const float* __restrict__ refpts,
                   __hip_bfloat16* __restrict__ msdah, long itemBase)
{
    const int  g    = threadIdx.x & 3;
    const long item = itemBase + (long)blockIdx.x * 64 + (threadIdx.x >> 2);
    const int  m    = (int)(item & (MHEADS - 1));
    const long nq   = item >> 3;
    const int  n    = (int)(nq / LQ);

    const float* frow = fused + nq * NFUSE;
    const float* lg   = frow + 256 + m * 16;
    const float  mx   = item_logsummax(lg);
    const float* off  = frow + m * 32;
    const float* rp   = refpts + nq * (NLEV * 2);
    const __hip_bfloat16* vb = value + (long)n * LEN_IN * CMODEL + m * DHEAD + g * 8;

    f32x8 acc = (f32x8)0.f;
#pragma unroll 1
    for (int j = 0; j < 16; ++j) {
        int st;
        PointW p = point_prep(j, off, rp, lg, mx, st);
        const __hip_bfloat16* base = vb + (long)st * CMODEL;
        if (p.w00 != 0.f) { u16x8 r = *(const u16x8*)&base[(long)p.i00 * CMODEL];
#pragma unroll
            for (int i = 0; i < 8; ++i) acc[i] += p.w00 * bf16val(r[i]); }
        if (p.w01 != 0.f) { u16x8 r = *(const u16x8*)&base[(long)p.i01 * CMODEL];
#pragma unroll
            for (int i = 0; i < 8; ++i) acc[i] += p.w01 * bf16val(r[i]); }
        if (p.w10 != 0.f) { u16x8 r = *(const u16x8*)&base[(long)p.i10 * CMODEL];
#pragma unroll
            for (int i = 0; i < 8; ++i) acc[i] += p.w10 * bf16val(r[i]); }
        if (p.w11 != 0.f) { u16x8 r = *(const u16x8*)&base[(long)p.i11 * CMODEL];
#pragma unroll
            for (int i = 0; i < 8; ++i) acc[i] += p.w11 * bf16val(r[i]); }
    }
    u16x8 oh;
#pragma unroll
    for (int i = 0; i < 8; ++i) oh[i] = bf16bits(acc[i]);
    *(u16x8*)&msdah[nq * CMODEL + m * DHEAD + g * 8] = oh;
}

// ---------- sampler 2L: 2 lanes/item, 16 ch/lane (2x16B taps) ---------------
__global__ __launch_bounds__(256)
void msda_sample2L(const __hip_bfloat16* __restrict__ value,
                   const float* __restrict__ fused,
                   const float* __restrict__ refpts,
                   __hip_bfloat16* __restrict__ msdah, long itemBase)
{
    const int  g    = threadIdx.x & 1;
    const long item = itemBase + (long)blockIdx.x * 128 + (threadIdx.x >> 1);
    const int  m    = (int)(item & (MHEADS - 1));
    const long nq   = item >> 3;
    const int  n    = (int)(nq / LQ);

    const float* frow = fused + nq * NFUSE;
    const float* lg   = frow + 256 + m * 16;
    const float  mx   = item_logsummax(lg);
    const float* off  = frow + m * 32;
    const float* rp   = refpts + nq * (NLEV * 2);
    const __hip_bfloat16* vb = value + (long)n * LEN_IN * CMODEL + m * DHEAD + g * 16;

    f32x8 acc0 = (f32x8)0.f, acc1 = (f32x8)0.f;
#pragma unroll 1
    for (int j = 0; j < 16; ++j) {
        int st;
        PointW p = point_prep(j, off, rp, lg, mx, st);
        const __hip_bfloat16* base = vb + (long)st * CMODEL;
        if (p.w00 != 0.f) {
            const __hip_bfloat16* q = &base[(long)p.i00 * CMODEL];
            u16x8 r0 = *(const u16x8*)q, r1 = *(const u16x8*)(q + 8);
#pragma unroll
            for (int i = 0; i < 8; ++i) { acc0[i] += p.w00 * bf16val(r0[i]);
                                          acc1[i] += p.w00 * bf16val(r1[i]); } }
        if (p.w01 != 0.f) {
            const __hip_bfloat16* q = &base[(long)p.i01 * CMODEL];
            u16x8 r0 = *(const u16x8*)q, r1 = *(const u16x8*)(q + 8);
#pragma unroll
            for (int i = 0; i < 8; ++i) { acc0[i] += p.w01 * bf16val(r0[i]);
                                          acc1[i] += p.w01 * bf16val(r1[i]); } }
        if (p.w10 != 0.f) {
            const __hip_bfloat16* q = &base[(long)p.i10 * CMODEL];
            u16x8 r0 = *(const u16x8*)q, r1 = *(const u16x8*)(q + 8);
#pragma unroll
            for (int i = 0; i < 8; ++i) { acc0[i] += p.w10 * bf16val(r0[i]);
                                          acc1[i] += p.w10 * bf16val(r1[i]); } }
        if (p.w11 != 0.f) {
            const __hip_bfloat16* q = &base[(long)p.i11 * CMODEL];
            u16x8 r0 = *(const u16x8*)q, r1 = *(const u16x8*)(q + 8);
#pragma unroll
            for (int i = 0; i < 8; ++i) { acc0[i] += p.w11 * bf16val(r0[i]);
                                          acc1[i] += p.w11 * bf16val(r1[i]); } }
    }
    u16x8 oh0, oh1;
#pragma unroll
    for (int i = 0; i < 8; ++i) { oh0[i] = bf16bits(acc0[i]); oh1[i] = bf16bits(acc1[i]); }
    __hip_bfloat16* dst = &msdah[nq * CMODEL + m * DHEAD + g * 16];
    *(u16x8*)dst       = oh0;
    *(u16x8*)(dst + 8) = oh1;
}

// ---------------------------------------------------------------------------
extern "C" void kernel_launch(void* const* d_in, const int* in_sizes, int n_in,
                              void* d_out, int out_size, void* d_ws, size_t ws_size,
                              hipStream_t stream)
{
    const float* query = (const float*)d_in[0];
    const float* refp  = (const float*)d_in[1];
    const float* inpf  = (const float*)d_in[2];
    const float* Wv    = (const float*)d_in[5];
    const float* bv    = (const float*)d_in[6];
    const float* Wo    = (const float*)d_in[7];
    const float* bo    = (const float*)d_in[8];
    const float* Wa    = (const float*)d_in[9];
    const float* ba    = (const float*)d_in[10];
    const float* Wout  = (const float*)d_in[11];
    const float* bout  = (const float*)d_in[12];
    float* out = (float*)d_out;

    // ws layout: valueh | msdah | q16 | i16 (bf16) | fused (f32) | weights | bcat
    __hip_bfloat16* valueh = (__hip_bfloat16*)d_ws;              // 24480*256
    __hip_bfloat16* msdah  = valueh + (long)MROWS * CMODEL;      // 24480*256
    __hip_bfloat16* q16    = msdah  + (long)MROWS * CMODEL;      // 24480*256
    __hip_bfloat16* i16    = q16    + (long)MROWS * CMODEL;      // 24480*256
    float* fused = (float*)(i16 + (long)MROWS * CMODEL);         // 24480*384 f32
    __hip_bfloat16* Wtv = (__hip_bfloat16*)(fused + (long)MROWS * NFUSE);
    __hip_bfloat16* Wtc = Wtv + 256 * 256;                       // [Wo|Wa]^T
    __hip_bfloat16* Wtt = Wtc + NFUSE * 256;                     // Wout^T
    float* bcat = (float*)(Wtt + 256 * 256);                     // 384

    const dim3 blk(256);
    const int convBlocks = (MROWS * CMODEL) / (256 * 8);         // 3060 exact

    // 0) input converts + weight prep
    conv_bf16<<<dim3(convBlocks), blk, 0, stream>>>(query, q16);
    conv_bf16<<<dim3(convBlocks), blk, 0, stream>>>(inpf,  i16);
    transpose_bf16<<<dim3(8, 8), blk, 0, stream>>>(Wv,   Wtv, 256, 256);
    transpose_bf16<<<dim3(8, 8), blk, 0, stream>>>(Wo,   Wtc, 256, 256);
    transpose_bf16<<<dim3(4, 8), blk, 0, stream>>>(Wa,   Wtc + 256 * 256, 256, 128);
    transpose_bf16<<<dim3(8, 8), blk, 0, stream>>>(Wout, Wtt, 256, 256);
    concat_bias<<<dim3(2), blk, 0, stream>>>(bo, ba, bcat);

    const int gy = (MROWS + 127) / 128;   // 192

    // 1) batched: value(bf16) = i16 @ Wv + bv  |  fused = q16 @ [Wo|Wa] + bcat
    gemm_stage1<<<dim3(5, gy), blk, 0, stream>>>(
        i16, Wtv, bv, valueh, q16, Wtc, bcat, fused);

    // 2) sampling — A/B: 4 lanes/item vs 2 lanes/item across halves
    {
        const long items = (long)NB * LQ * MHEADS;   // 195840
        const long half  = items / 2;                // 97920
        msda_sample4L<<<dim3((int)(half / 64)),  blk, 0, stream>>>(
            valueh, fused, refp, msdah, 0L);
        msda_sample2L<<<dim3((int)(half / 128)), blk, 0, stream>>>(
            valueh, fused, refp, msdah, half);
    }

    // 3) out = msdah @ Wout + bout
    gemm_stage2<<<dim3(2, gy), blk, 0, stream>>>(msdah, Wtt, bout, out);
}